// Round 4
// baseline (237.060 us; speedup 1.0000x reference)
//
#include <hip/hip_runtime.h>
#include <math.h>

#define T_BINS 350
#define REF_LEN 32
#define NB 32
#define NPIX 3072
#define N1 240
#define N2 10
#define NVAL 256

// ---------------------------------------------------------------------------
// Kernel 1 (fused): blocks 0..31 -> per-batch CSR build; blocks 32..223 ->
// 64x64 tiled transpose of w1; block 224 -> inverse bin map inv[t]=v or -1.
// (unchanged, proven)
// ---------------------------------------------------------------------------
__global__ void prep(const int* __restrict__ inp,
                     int* __restrict__ pix,    // [NB][NPIX]
                     int* __restrict__ offs,   // [NB][NVAL]
                     int* __restrict__ cnts,   // [NB][NVAL]
                     const float* __restrict__ w1,
                     float* __restrict__ w1t,
                     const int* __restrict__ table,
                     int* __restrict__ inv)    // [T_BINS]
{
    __shared__ int lc[NVAL];
    __shared__ int ls[NVAL];
    __shared__ int lslot[NVAL];
    __shared__ float tile[64][65];
    __shared__ int linv[T_BINS];

    const int tid = threadIdx.x;

    if (blockIdx.x < NB) {
        // ---- CSR build for batch b ----
        const int b = blockIdx.x;
        lc[tid] = 0;
        __syncthreads();

        int vals[12];
        #pragma unroll
        for (int i = 0; i < 12; ++i) {
            int v = inp[b * NPIX + i * 256 + tid];   // coalesced
            vals[i] = v;
            atomicAdd(&lc[v], 1);
        }
        __syncthreads();

        int x = lc[tid];
        ls[tid] = x;
        __syncthreads();
        for (int d = 1; d < 256; d <<= 1) {
            int y = (tid >= d) ? ls[tid - d] : 0;
            __syncthreads();
            ls[tid] += y;
            __syncthreads();
        }
        int excl = ls[tid] - x;
        offs[b * NVAL + tid] = excl;
        cnts[b * NVAL + tid] = x;
        lslot[tid] = excl;
        __syncthreads();

        #pragma unroll
        for (int i = 0; i < 12; ++i) {
            int slot = atomicAdd(&lslot[vals[i]], 1);
            pix[b * NPIX + slot] = i * 256 + tid;
        }
    } else if (blockIdx.x < NB + 192) {
        // ---- transpose tile ----
        const int tt = blockIdx.x - NB;       // 0..191
        const int p0 = (tt % 48) * 64;
        const int n0 = (tt / 48) * 64;
        const int c  = tid & 63;
        const int r0 = tid >> 6;              // 0..3

        #pragma unroll
        for (int i = 0; i < 16; ++i) {
            int n = n0 + r0 + i * 4;
            if (n < N1) tile[r0 + i * 4][c] = w1[n * NPIX + p0 + c];
        }
        __syncthreads();
        #pragma unroll
        for (int i = 0; i < 16; ++i) {
            int p = p0 + r0 + i * 4;
            int n = n0 + c;
            if (n < N1) w1t[p * N1 + n] = tile[c][r0 + i * 4];
        }
    } else {
        // ---- inverse bin map (table is injective value->bin) ----
        for (int i = tid; i < T_BINS; i += 256) linv[i] = -1;
        __syncthreads();
        if (tid < NVAL) linv[table[tid]] = tid;
        __syncthreads();
        for (int i = tid; i < T_BINS; i += 256) inv[i] = linv[i];
    }
}

// ---------------------------------------------------------------------------
// Kernel 2: W[b][v][n] = sum over pixels with value v of w1t[p, n].
// Ascending-order fp64 accumulate, single fp32 rounding (verified round 1).
// ---------------------------------------------------------------------------
__global__ void compute_w(const float* __restrict__ w1t,
                          const int* __restrict__ pix,
                          const int* __restrict__ offs,
                          const int* __restrict__ cnts,
                          float* __restrict__ W)     // [NB][NVAL][N1]
{
    const int b   = blockIdx.y;
    const int tid = threadIdx.x;
    if (tid >= N1) return;

    for (int vv = 0; vv < 4; ++vv) {
        const int v = blockIdx.x * 4 + vv;
        const int cnt = cnts[b * NVAL + v];
        const int* pl = pix + b * NPIX + offs[b * NVAL + v];
        double acc = 0.0;
        int i = 0;
        for (; i + 4 <= cnt; i += 4) {
            int p0 = pl[i], p1 = pl[i + 1], p2 = pl[i + 2], p3 = pl[i + 3];
            double w0  = (double)w1t[p0 * N1 + tid];
            double w1v = (double)w1t[p1 * N1 + tid];
            double w2v = (double)w1t[p2 * N1 + tid];
            double w3  = (double)w1t[p3 * N1 + tid];
            acc += w0; acc += w1v; acc += w2v; acc += w3;   // ascending order
        }
        for (; i < cnt; ++i)
            acc += (double)w1t[pl[i] * N1 + tid];
        W[((size_t)b * NVAL + v) * N1 + tid] = (float)acc;
    }
}

// ---------------------------------------------------------------------------
// Dynamics math (identical constants/ops to all prior rounds).
// ---------------------------------------------------------------------------
#define DYN_CONSTS \
    const double A    = 0.9048374180359595;     \
    const double C    = 0.2718281828459045;     \
    const double Ar   = 0.36787944117144233;    \
    const double Cr   = -54.365636569180904;    \
    const double C31A = 1.0671679036256927e-12; \
    const double C31B = 3.4424771084699765e-14;

#define DYN_CORE(uin)                                         \
        q = A * (q + p);                                      \
        p = A * p + (uin);                                    \
        double vm = C * q + Cr * Q;                           \
        unsigned int sb = (vm >= 10.0) ? 1u : 0u;             \
        double s = (double)sb;                                \
        double sel31 = (hist & 0x80000000u) ? C31A : 0.0;     \
        double sel30 = (hist & 0x40000000u) ? C31B : 0.0;     \
        Q = Ar * (Q + P - sel31);                             \
        P = s + (Ar * P - sel30);                             \
        hist = (hist << 1) | sb;

// ---------------------------------------------------------------------------
// Kernel 3: layer-1 dynamics. 128 blocks x 64 threads.
// __launch_bounds__(64, 1): round-3 post-mortem — bare __launch_bounds__(64)
// allocated only 40 VGPRs (< the 56 needed for cb[14]+nb[14] fp64 prefetch)
// and spilled both buffers to scratch -> 103us. With only 128 waves on a
// 256-CU chip (<=1 wave/CU) occupancy is free; demand the full budget so
// the prefetch arrays live in registers and 14 loads stay in flight.
// ---------------------------------------------------------------------------
__global__ __launch_bounds__(64, 1) void layer1_dyn(
                           const float* __restrict__ W,     // [NB][NVAL][N1]
                           const int* __restrict__ inv,     // [T_BINS]
                           unsigned long long* __restrict__ s1m) // [NB][T][4]
{
    __shared__ int linv[T_BINS];

    const int tid = threadIdx.x;             // 0..63
    const int b   = blockIdx.x >> 2;
    const int k   = blockIdx.x & 3;          // n-tile
    const int n   = k * 64 + tid;
    const bool valid = (n < N1);

    for (int i = tid; i < T_BINS; i += 64) linv[i] = inv[i];
    __syncthreads();

    const float* Wb = W + (size_t)b * NVAL * N1 + (valid ? n : 0);
    unsigned long long* mp = s1m + ((size_t)b * T_BINS) * 4 + k;

    DYN_CONSTS
    double p = 0.0, q = 0.0, P = 0.0, Q = 0.0;
    unsigned int hist = 0u;

    double cb[14], nb[14];
    #pragma unroll
    for (int i = 0; i < 14; ++i) {
        int v = linv[i];
        cb[i] = (valid && v >= 0) ? (double)Wb[(size_t)v * N1] : 0.0;
    }

    for (int t0 = 0; t0 < T_BINS; t0 += 14) {
        if (t0 + 14 < T_BINS) {
            #pragma unroll
            for (int i = 0; i < 14; ++i) {
                int v = linv[t0 + 14 + i];
                nb[i] = (valid && v >= 0) ? (double)Wb[(size_t)v * N1] : 0.0;
            }
        }
        #pragma unroll
        for (int i = 0; i < 14; ++i) {
            DYN_CORE(cb[i])
            unsigned long long msk = __ballot(sb != 0u);
            if (tid == 0) mp[(size_t)(t0 + i) * 4] = msk;
        }
        #pragma unroll
        for (int i = 0; i < 14; ++i) cb[i] = nb[i];
    }
}

// ---------------------------------------------------------------------------
// Kernel 4 (merged u2 + layer2): one block per batch, 256 threads.
//   phase A: stage s1m[b] + w2 in LDS; u2[t][m] via bit-walk (identical kk
//            asc / ffs asc order -> bit-identical sums).
//   phase B: layer-2 IIR on 10 lanes with 14-deep LDS prefetch; spikes
//            overwrite su2 in place.
//   phase C: coalesced store out[b][m][t].
// __launch_bounds__(256, 1) prevents the register-starvation spill (worked:
// absent from round-3 top-5).
// ---------------------------------------------------------------------------
__global__ __launch_bounds__(256, 1) void u2l2(
        const unsigned long long* __restrict__ s1m,  // [NB][T][4]
        const float* __restrict__ w2,                // [N2][N1]
        float* __restrict__ out)                     // [NB][N2][T]
{
    __shared__ unsigned long long sm[T_BINS][4];   // 11.2 KB
    __shared__ float lw2[N2][N1];                  // 9.6 KB
    __shared__ float su2[T_BINS][N2];              // 14 KB

    const int tid = threadIdx.x;
    const int b   = blockIdx.x;

    for (int i = tid; i < N2 * N1; i += 256) lw2[i / N1][i % N1] = w2[i];
    {
        const unsigned long long* sp = s1m + (size_t)b * T_BINS * 4;
        unsigned long long* dp = &sm[0][0];
        for (int i = tid; i < T_BINS * 4; i += 256) dp[i] = sp[i];
    }
    __syncthreads();

    // ---- phase A: u2 = masks · w2 ----
    for (int id = tid; id < T_BINS * N2; id += 256) {
        const int t = id / N2;
        const int m = id - t * N2;
        double acc = 0.0;
        #pragma unroll
        for (int kk = 0; kk < 4; ++kk) {
            unsigned long long msk = sm[t][kk];
            while (msk) {
                int j = __ffsll(msk) - 1;
                acc += (double)lw2[m][kk * 64 + j];
                msk &= msk - 1;
            }
        }
        su2[t][m] = (float)acc;
    }
    __syncthreads();

    // ---- phase B: layer-2 IIR on 10 lanes ----
    if (tid < N2) {
        const int m = tid;
        DYN_CONSTS
        double p = 0.0, q = 0.0, P = 0.0, Q = 0.0;
        unsigned int hist = 0u;

        double cb[14], nb[14];
        #pragma unroll
        for (int i = 0; i < 14; ++i) cb[i] = (double)su2[i][m];

        for (int t0 = 0; t0 < T_BINS; t0 += 14) {
            if (t0 + 14 < T_BINS) {
                #pragma unroll
                for (int i = 0; i < 14; ++i) nb[i] = (double)su2[t0 + 14 + i][m];
            }
            #pragma unroll
            for (int i = 0; i < 14; ++i) {
                DYN_CORE(cb[i])
                su2[t0 + i][m] = (float)s;   // overwrite u2 with spike
            }
            #pragma unroll
            for (int i = 0; i < 14; ++i) cb[i] = nb[i];
        }
    }
    __syncthreads();

    // ---- phase C: coalesced store out[b][m][t] ----
    float* ob = out + (size_t)b * N2 * T_BINS;
    for (int id = tid; id < N2 * T_BINS; id += 256) {
        const int m = id / T_BINS;
        const int t = id - m * T_BINS;
        ob[id] = su2[t][m];
    }
}

// ---------------------------------------------------------------------------
extern "C" void kernel_launch(void* const* d_in, const int* in_sizes, int n_in,
                              void* d_out, int out_size, void* d_ws, size_t ws_size,
                              hipStream_t stream) {
    const int*   inp   = (const int*)d_in[0];    // [32,3,32,32]
    const int*   table = (const int*)d_in[1];    // [256]
    const float* w1    = (const float*)d_in[2];  // [240,3072]
    const float* w2    = (const float*)d_in[3];  // [10,240]
    float* out = (float*)d_out;                  // [32,10,350]

    char* ws = (char*)d_ws;
    size_t off = 0;
    float* W   = (float*)(ws + off);  off += (size_t)NB * NVAL * N1 * 4;     // 7.86 MB
    float* w1t = (float*)(ws + off);  off += (size_t)NPIX * N1 * 4;          // 2.9 MB
    unsigned long long* s1m = (unsigned long long*)(ws + off);
    off += (size_t)NB * T_BINS * 4 * 8;                                      // 358 KB
    int*   pix = (int*)(ws + off);    off += (size_t)NB * NPIX * 4;
    int*  offs = (int*)(ws + off);    off += (size_t)NB * NVAL * 4;
    int*  cnts = (int*)(ws + off);    off += (size_t)NB * NVAL * 4;
    int*   inv = (int*)(ws + off);    off += (size_t)T_BINS * 4;

    prep<<<NB + 192 + 1, 256, 0, stream>>>(inp, pix, offs, cnts, w1, w1t, table, inv);
    compute_w<<<dim3(NVAL / 4, NB), 256, 0, stream>>>(w1t, pix, offs, cnts, W);
    layer1_dyn<<<NB * 4, 64, 0, stream>>>(W, inv, s1m);
    u2l2<<<NB, 256, 0, stream>>>(s1m, w2, out);
}

// Round 5
// 171.750 us; speedup vs baseline: 1.3803x; 1.3803x over previous
//
#include <hip/hip_runtime.h>
#include <math.h>

#define T_BINS 350
#define REF_LEN 32
#define NB 32
#define NPIX 3072
#define N1 240
#define N2 10
#define NVAL 256
#define WROW 256                  // padded row width (floats) in W
#define WROWS (NVAL + 1)          // 256 value rows + 1 zero row

// ---------------------------------------------------------------------------
// Kernel 1 (fused): blocks 0..31 -> per-batch CSR build; blocks 32..223 ->
// 64x64 tiled transpose of w1; block 224 -> inverse bin map inv[t]=v or -1.
// (unchanged, proven)
// ---------------------------------------------------------------------------
__global__ void prep(const int* __restrict__ inp,
                     int* __restrict__ pix,    // [NB][NPIX]
                     int* __restrict__ offs,   // [NB][NVAL]
                     int* __restrict__ cnts,   // [NB][NVAL]
                     const float* __restrict__ w1,
                     float* __restrict__ w1t,
                     const int* __restrict__ table,
                     int* __restrict__ inv)    // [T_BINS]
{
    __shared__ int lc[NVAL];
    __shared__ int ls[NVAL];
    __shared__ int lslot[NVAL];
    __shared__ float tile[64][65];
    __shared__ int linv[T_BINS];

    const int tid = threadIdx.x;

    if (blockIdx.x < NB) {
        // ---- CSR build for batch b ----
        const int b = blockIdx.x;
        lc[tid] = 0;
        __syncthreads();

        int vals[12];
        #pragma unroll
        for (int i = 0; i < 12; ++i) {
            int v = inp[b * NPIX + i * 256 + tid];   // coalesced
            vals[i] = v;
            atomicAdd(&lc[v], 1);
        }
        __syncthreads();

        int x = lc[tid];
        ls[tid] = x;
        __syncthreads();
        for (int d = 1; d < 256; d <<= 1) {
            int y = (tid >= d) ? ls[tid - d] : 0;
            __syncthreads();
            ls[tid] += y;
            __syncthreads();
        }
        int excl = ls[tid] - x;
        offs[b * NVAL + tid] = excl;
        cnts[b * NVAL + tid] = x;
        lslot[tid] = excl;
        __syncthreads();

        #pragma unroll
        for (int i = 0; i < 12; ++i) {
            int slot = atomicAdd(&lslot[vals[i]], 1);
            pix[b * NPIX + slot] = i * 256 + tid;
        }
    } else if (blockIdx.x < NB + 192) {
        // ---- transpose tile ----
        const int tt = blockIdx.x - NB;       // 0..191
        const int p0 = (tt % 48) * 64;
        const int n0 = (tt / 48) * 64;
        const int c  = tid & 63;
        const int r0 = tid >> 6;              // 0..3

        #pragma unroll
        for (int i = 0; i < 16; ++i) {
            int n = n0 + r0 + i * 4;
            if (n < N1) tile[r0 + i * 4][c] = w1[n * NPIX + p0 + c];
        }
        __syncthreads();
        #pragma unroll
        for (int i = 0; i < 16; ++i) {
            int p = p0 + r0 + i * 4;
            int n = n0 + c;
            if (n < N1) w1t[p * N1 + n] = tile[c][r0 + i * 4];
        }
    } else {
        // ---- inverse bin map (table is injective value->bin) ----
        for (int i = tid; i < T_BINS; i += 256) linv[i] = -1;
        __syncthreads();
        if (tid < NVAL) linv[table[tid]] = tid;
        __syncthreads();
        for (int i = tid; i < T_BINS; i += 256) inv[i] = linv[i];
    }
}

// ---------------------------------------------------------------------------
// Kernel 2: W[b][v][n] = sum over pixels with value v of w1t[p, n].
// Padded layout [NB][257][256]: cols 240..255 = 0, row 256 = 0, so the
// dynamics kernel can load UNCONDITIONALLY for every lane and every bin.
// Ascending-order fp64 accumulate, single fp32 rounding (verified).
// ---------------------------------------------------------------------------
__global__ void compute_w(const float* __restrict__ w1t,
                          const int* __restrict__ pix,
                          const int* __restrict__ offs,
                          const int* __restrict__ cnts,
                          float* __restrict__ W)     // [NB][WROWS][WROW]
{
    const int b   = blockIdx.y;
    const int tid = threadIdx.x;

    for (int vv = 0; vv < 4; ++vv) {
        const int v = blockIdx.x * 4 + vv;
        float outv = 0.0f;
        if (tid < N1) {
            const int cnt = cnts[b * NVAL + v];
            const int* pl = pix + b * NPIX + offs[b * NVAL + v];
            double acc = 0.0;
            int i = 0;
            for (; i + 4 <= cnt; i += 4) {
                int p0 = pl[i], p1 = pl[i + 1], p2 = pl[i + 2], p3 = pl[i + 3];
                double w0  = (double)w1t[p0 * N1 + tid];
                double w1v = (double)w1t[p1 * N1 + tid];
                double w2v = (double)w1t[p2 * N1 + tid];
                double w3  = (double)w1t[p3 * N1 + tid];
                acc += w0; acc += w1v; acc += w2v; acc += w3;   // ascending order
            }
            for (; i < cnt; ++i)
                acc += (double)w1t[pl[i] * N1 + tid];
            outv = (float)acc;
        }
        W[((size_t)b * WROWS + v) * WROW + tid] = outv;
    }
    // zero row (v = NVAL) for empty time bins
    if (blockIdx.x == 0)
        W[((size_t)b * WROWS + NVAL) * WROW + tid] = 0.0f;
}

// ---------------------------------------------------------------------------
// Dynamics math (identical constants/ops to all prior rounds).
// ---------------------------------------------------------------------------
#define DYN_CONSTS \
    const double A    = 0.9048374180359595;     \
    const double C    = 0.2718281828459045;     \
    const double Ar   = 0.36787944117144233;    \
    const double Cr   = -54.365636569180904;    \
    const double C31A = 1.0671679036256927e-12; \
    const double C31B = 3.4424771084699765e-14;

#define DYN_CORE(uin)                                         \
        q = A * (q + p);                                      \
        p = A * p + (uin);                                    \
        double vm = C * q + Cr * Q;                           \
        unsigned int sb = (vm >= 10.0) ? 1u : 0u;             \
        double s = (double)sb;                                \
        double sel31 = (hist & 0x80000000u) ? C31A : 0.0;     \
        double sel30 = (hist & 0x40000000u) ? C31B : 0.0;     \
        Q = Ar * (Q + P - sel31);                             \
        P = s + (Ar * P - sel30);                             \
        hist = (hist << 1) | sb;

// ---------------------------------------------------------------------------
// Kernel 3: layer-1 dynamics. 128 blocks x 64 threads.
// Round-4 post-mortem: 102us was NOT a register-starvation spill (VGPR=40
// with (64,1) too). It was 703 cyc/step = one latency round-trip per step:
// the conditional gather `(valid && v>=0) ? Wb[v*N1] : 0` forced exec-mask
// codegen + LDS-dependent addressing, so the compiler issued loads lazily
// instead of 14-in-flight. Fix: padded W (zero row/cols) makes every load
// unconditional; byte offsets staged in LDS, hoisted 14-at-a-time into
// registers, then 14 back-to-back independent loads (round-0's proven
// dense-load shape).
// ---------------------------------------------------------------------------
__global__ __launch_bounds__(64, 1) void layer1_dyn(
                           const float* __restrict__ W,     // [NB][WROWS][WROW]
                           const int* __restrict__ inv,     // [T_BINS]
                           unsigned long long* __restrict__ s1m) // [NB][T][4]
{
    __shared__ int loff[T_BINS];             // byte offset of row for bin t

    const int tid = threadIdx.x;             // 0..63
    const int b   = blockIdx.x >> 2;
    const int k   = blockIdx.x & 3;          // n-tile
    const int n   = k * 64 + tid;            // 0..255, always a legal column

    for (int i = tid; i < T_BINS; i += 64) {
        int v = inv[i];
        loff[i] = ((v >= 0) ? v : NVAL) * (WROW * 4);
    }
    __syncthreads();

    const char* wb = (const char*)W
                   + ((size_t)b * WROWS) * (WROW * 4) + (size_t)n * 4;
    unsigned long long* mp = s1m + ((size_t)b * T_BINS) * 4 + k;

    DYN_CONSTS
    double p = 0.0, q = 0.0, P = 0.0, Q = 0.0;
    unsigned int hist = 0u;

    double cb[14], nb[14];
    {
        int of[14];
        #pragma unroll
        for (int i = 0; i < 14; ++i) of[i] = loff[i];
        #pragma unroll
        for (int i = 0; i < 14; ++i)
            cb[i] = (double)*(const float*)(wb + of[i]);
    }

    for (int t0 = 0; t0 < T_BINS; t0 += 14) {
        if (t0 + 14 < T_BINS) {
            int of[14];
            #pragma unroll
            for (int i = 0; i < 14; ++i) of[i] = loff[t0 + 14 + i];
            #pragma unroll
            for (int i = 0; i < 14; ++i)
                nb[i] = (double)*(const float*)(wb + of[i]);
        }
        #pragma unroll
        for (int i = 0; i < 14; ++i) {
            DYN_CORE(cb[i])
            unsigned long long msk = __ballot(sb != 0u);
            if (tid == 0) mp[(size_t)(t0 + i) * 4] = msk;
        }
        #pragma unroll
        for (int i = 0; i < 14; ++i) cb[i] = nb[i];
    }
}

// ---------------------------------------------------------------------------
// Kernel 4 (merged u2 + layer2): one block per batch, 256 threads.
// (unchanged — absent from round-3/4 top-5, i.e. < fill floor)
// ---------------------------------------------------------------------------
__global__ __launch_bounds__(256, 1) void u2l2(
        const unsigned long long* __restrict__ s1m,  // [NB][T][4]
        const float* __restrict__ w2,                // [N2][N1]
        float* __restrict__ out)                     // [NB][N2][T]
{
    __shared__ unsigned long long sm[T_BINS][4];   // 11.2 KB
    __shared__ float lw2[N2][N1];                  // 9.6 KB
    __shared__ float su2[T_BINS][N2];              // 14 KB

    const int tid = threadIdx.x;
    const int b   = blockIdx.x;

    for (int i = tid; i < N2 * N1; i += 256) lw2[i / N1][i % N1] = w2[i];
    {
        const unsigned long long* sp = s1m + (size_t)b * T_BINS * 4;
        unsigned long long* dp = &sm[0][0];
        for (int i = tid; i < T_BINS * 4; i += 256) dp[i] = sp[i];
    }
    __syncthreads();

    // ---- phase A: u2 = masks · w2 (kk asc / ffs asc -> bit-identical) ----
    for (int id = tid; id < T_BINS * N2; id += 256) {
        const int t = id / N2;
        const int m = id - t * N2;
        double acc = 0.0;
        #pragma unroll
        for (int kk = 0; kk < 4; ++kk) {
            unsigned long long msk = sm[t][kk];
            while (msk) {
                int j = __ffsll(msk) - 1;
                acc += (double)lw2[m][kk * 64 + j];
                msk &= msk - 1;
            }
        }
        su2[t][m] = (float)acc;
    }
    __syncthreads();

    // ---- phase B: layer-2 IIR on 10 lanes ----
    if (tid < N2) {
        const int m = tid;
        DYN_CONSTS
        double p = 0.0, q = 0.0, P = 0.0, Q = 0.0;
        unsigned int hist = 0u;

        double cb[14], nb[14];
        #pragma unroll
        for (int i = 0; i < 14; ++i) cb[i] = (double)su2[i][m];

        for (int t0 = 0; t0 < T_BINS; t0 += 14) {
            if (t0 + 14 < T_BINS) {
                #pragma unroll
                for (int i = 0; i < 14; ++i) nb[i] = (double)su2[t0 + 14 + i][m];
            }
            #pragma unroll
            for (int i = 0; i < 14; ++i) {
                DYN_CORE(cb[i])
                su2[t0 + i][m] = (float)s;   // overwrite u2 with spike
            }
            #pragma unroll
            for (int i = 0; i < 14; ++i) cb[i] = nb[i];
        }
    }
    __syncthreads();

    // ---- phase C: coalesced store out[b][m][t] ----
    float* ob = out + (size_t)b * N2 * T_BINS;
    for (int id = tid; id < N2 * T_BINS; id += 256) {
        const int m = id / T_BINS;
        const int t = id - m * T_BINS;
        ob[id] = su2[t][m];
    }
}

// ---------------------------------------------------------------------------
extern "C" void kernel_launch(void* const* d_in, const int* in_sizes, int n_in,
                              void* d_out, int out_size, void* d_ws, size_t ws_size,
                              hipStream_t stream) {
    const int*   inp   = (const int*)d_in[0];    // [32,3,32,32]
    const int*   table = (const int*)d_in[1];    // [256]
    const float* w1    = (const float*)d_in[2];  // [240,3072]
    const float* w2    = (const float*)d_in[3];  // [10,240]
    float* out = (float*)d_out;                  // [32,10,350]

    char* ws = (char*)d_ws;
    size_t off = 0;
    float* W   = (float*)(ws + off);  off += (size_t)NB * WROWS * WROW * 4;  // 8.4 MB
    float* w1t = (float*)(ws + off);  off += (size_t)NPIX * N1 * 4;          // 2.9 MB
    unsigned long long* s1m = (unsigned long long*)(ws + off);
    off += (size_t)NB * T_BINS * 4 * 8;                                      // 358 KB
    int*   pix = (int*)(ws + off);    off += (size_t)NB * NPIX * 4;
    int*  offs = (int*)(ws + off);    off += (size_t)NB * NVAL * 4;
    int*  cnts = (int*)(ws + off);    off += (size_t)NB * NVAL * 4;
    int*   inv = (int*)(ws + off);    off += (size_t)T_BINS * 4;

    prep<<<NB + 192 + 1, 256, 0, stream>>>(inp, pix, offs, cnts, w1, w1t, table, inv);
    compute_w<<<dim3(NVAL / 4, NB), 256, 0, stream>>>(w1t, pix, offs, cnts, W);
    layer1_dyn<<<NB * 4, 64, 0, stream>>>(W, inv, s1m);
    u2l2<<<NB, 256, 0, stream>>>(s1m, w2, out);
}

// Round 6
// 169.573 us; speedup vs baseline: 1.3980x; 1.0128x over previous
//
#include <hip/hip_runtime.h>
#include <math.h>

#define T_BINS 350
#define REF_LEN 32
#define NB 32
#define NPIX 3072
#define N1 240
#define N2 10
#define NVAL 256
#define WROW 256                  // padded row width (floats) in W
#define WROWS (NVAL + 1)          // 256 value rows + 1 zero row

// ---------------------------------------------------------------------------
// Kernel 1 (fused): blocks 0..31 -> per-batch CSR build; blocks 32..223 ->
// 64x64 tiled transpose of w1; block 224 -> inverse bin map inv[t]=v or -1.
// (unchanged, proven)
// ---------------------------------------------------------------------------
__global__ void prep(const int* __restrict__ inp,
                     int* __restrict__ pix,    // [NB][NPIX]
                     int* __restrict__ offs,   // [NB][NVAL]
                     int* __restrict__ cnts,   // [NB][NVAL]
                     const float* __restrict__ w1,
                     float* __restrict__ w1t,
                     const int* __restrict__ table,
                     int* __restrict__ inv)    // [T_BINS]
{
    __shared__ int lc[NVAL];
    __shared__ int ls[NVAL];
    __shared__ int lslot[NVAL];
    __shared__ float tile[64][65];
    __shared__ int linv[T_BINS];

    const int tid = threadIdx.x;

    if (blockIdx.x < NB) {
        // ---- CSR build for batch b ----
        const int b = blockIdx.x;
        lc[tid] = 0;
        __syncthreads();

        int vals[12];
        #pragma unroll
        for (int i = 0; i < 12; ++i) {
            int v = inp[b * NPIX + i * 256 + tid];   // coalesced
            vals[i] = v;
            atomicAdd(&lc[v], 1);
        }
        __syncthreads();

        int x = lc[tid];
        ls[tid] = x;
        __syncthreads();
        for (int d = 1; d < 256; d <<= 1) {
            int y = (tid >= d) ? ls[tid - d] : 0;
            __syncthreads();
            ls[tid] += y;
            __syncthreads();
        }
        int excl = ls[tid] - x;
        offs[b * NVAL + tid] = excl;
        cnts[b * NVAL + tid] = x;
        lslot[tid] = excl;
        __syncthreads();

        #pragma unroll
        for (int i = 0; i < 12; ++i) {
            int slot = atomicAdd(&lslot[vals[i]], 1);
            pix[b * NPIX + slot] = i * 256 + tid;
        }
    } else if (blockIdx.x < NB + 192) {
        // ---- transpose tile ----
        const int tt = blockIdx.x - NB;       // 0..191
        const int p0 = (tt % 48) * 64;
        const int n0 = (tt / 48) * 64;
        const int c  = tid & 63;
        const int r0 = tid >> 6;              // 0..3

        #pragma unroll
        for (int i = 0; i < 16; ++i) {
            int n = n0 + r0 + i * 4;
            if (n < N1) tile[r0 + i * 4][c] = w1[n * NPIX + p0 + c];
        }
        __syncthreads();
        #pragma unroll
        for (int i = 0; i < 16; ++i) {
            int p = p0 + r0 + i * 4;
            int n = n0 + c;
            if (n < N1) w1t[p * N1 + n] = tile[c][r0 + i * 4];
        }
    } else {
        // ---- inverse bin map (table is injective value->bin) ----
        for (int i = tid; i < T_BINS; i += 256) linv[i] = -1;
        __syncthreads();
        if (tid < NVAL) linv[table[tid]] = tid;
        __syncthreads();
        for (int i = tid; i < T_BINS; i += 256) inv[i] = linv[i];
    }
}

// ---------------------------------------------------------------------------
// Kernel 2: W[b][v][n] = sum over pixels with value v of w1t[p, n].
// Padded layout [NB][257][256]: cols 240..255 = 0, row 256 = 0, so the
// dynamics kernel can load UNCONDITIONALLY for every lane and every bin.
// Ascending-order fp64 accumulate, single fp32 rounding (verified).
// ---------------------------------------------------------------------------
__global__ void compute_w(const float* __restrict__ w1t,
                          const int* __restrict__ pix,
                          const int* __restrict__ offs,
                          const int* __restrict__ cnts,
                          float* __restrict__ W)     // [NB][WROWS][WROW]
{
    const int b   = blockIdx.y;
    const int tid = threadIdx.x;

    for (int vv = 0; vv < 4; ++vv) {
        const int v = blockIdx.x * 4 + vv;
        float outv = 0.0f;
        if (tid < N1) {
            const int cnt = cnts[b * NVAL + v];
            const int* pl = pix + b * NPIX + offs[b * NVAL + v];
            double acc = 0.0;
            int i = 0;
            for (; i + 4 <= cnt; i += 4) {
                int p0 = pl[i], p1 = pl[i + 1], p2 = pl[i + 2], p3 = pl[i + 3];
                double w0  = (double)w1t[p0 * N1 + tid];
                double w1v = (double)w1t[p1 * N1 + tid];
                double w2v = (double)w1t[p2 * N1 + tid];
                double w3  = (double)w1t[p3 * N1 + tid];
                acc += w0; acc += w1v; acc += w2v; acc += w3;   // ascending order
            }
            for (; i < cnt; ++i)
                acc += (double)w1t[pl[i] * N1 + tid];
            outv = (float)acc;
        }
        W[((size_t)b * WROWS + v) * WROW + tid] = outv;
    }
    // zero row (v = NVAL) for empty time bins
    if (blockIdx.x == 0)
        W[((size_t)b * WROWS + NVAL) * WROW + tid] = 0.0f;
}

// ---------------------------------------------------------------------------
// Dynamics math (identical constants/ops to all prior rounds).
// ---------------------------------------------------------------------------
#define DYN_CONSTS \
    const double A    = 0.9048374180359595;     \
    const double C    = 0.2718281828459045;     \
    const double Ar   = 0.36787944117144233;    \
    const double Cr   = -54.365636569180904;    \
    const double C31A = 1.0671679036256927e-12; \
    const double C31B = 3.4424771084699765e-14;

#define DYN_CORE(uin)                                         \
        q = A * (q + p);                                      \
        p = A * p + (uin);                                    \
        double vm = C * q + Cr * Q;                           \
        unsigned int sb = (vm >= 10.0) ? 1u : 0u;             \
        double s = (double)sb;                                \
        double sel31 = (hist & 0x80000000u) ? C31A : 0.0;     \
        double sel30 = (hist & 0x40000000u) ? C31B : 0.0;     \
        Q = Ar * (Q + P - sel31);                             \
        P = s + (Ar * P - sel30);                             \
        hist = (hist << 1) | sb;

// ---------------------------------------------------------------------------
// Kernel 3: layer-1 dynamics. 128 blocks x 64 threads.
// Round-5 change: prefetch buffers are FLOAT, not double (data is fp32 in
// memory; f32->f64 at use is exact). cb+nb drop 56->28 VGPRs, so the whole
// working set fits the register budget and all 14 gather loads stay in
// flight (rounds 3/4 showed the fp64 buffers pushed allocation past what
// the allocator would give, serializing one latency round-trip per step).
// ---------------------------------------------------------------------------
__global__ __launch_bounds__(64, 1) void layer1_dyn(
                           const float* __restrict__ W,     // [NB][WROWS][WROW]
                           const int* __restrict__ inv,     // [T_BINS]
                           unsigned long long* __restrict__ s1m) // [NB][T][4]
{
    __shared__ int loff[T_BINS];             // byte offset of row for bin t

    const int tid = threadIdx.x;             // 0..63
    const int b   = blockIdx.x >> 2;
    const int k   = blockIdx.x & 3;          // n-tile
    const int n   = k * 64 + tid;            // 0..255, always a legal column

    for (int i = tid; i < T_BINS; i += 64) {
        int v = inv[i];
        loff[i] = ((v >= 0) ? v : NVAL) * (WROW * 4);
    }
    __syncthreads();

    const char* wb = (const char*)W
                   + ((size_t)b * WROWS) * (WROW * 4) + (size_t)n * 4;
    unsigned long long* mp = s1m + ((size_t)b * T_BINS) * 4 + k;

    DYN_CONSTS
    double p = 0.0, q = 0.0, P = 0.0, Q = 0.0;
    unsigned int hist = 0u;

    float cb[14], nb[14];
    {
        int of[14];
        #pragma unroll
        for (int i = 0; i < 14; ++i) of[i] = loff[i];
        #pragma unroll
        for (int i = 0; i < 14; ++i)
            cb[i] = *(const float*)(wb + of[i]);
    }

    for (int t0 = 0; t0 < T_BINS; t0 += 14) {
        if (t0 + 14 < T_BINS) {
            int of[14];
            #pragma unroll
            for (int i = 0; i < 14; ++i) of[i] = loff[t0 + 14 + i];
            #pragma unroll
            for (int i = 0; i < 14; ++i)
                nb[i] = *(const float*)(wb + of[i]);
        }
        #pragma unroll
        for (int i = 0; i < 14; ++i) {
            DYN_CORE((double)cb[i])
            unsigned long long msk = __ballot(sb != 0u);
            if (tid == 0) mp[(size_t)(t0 + i) * 4] = msk;
        }
        #pragma unroll
        for (int i = 0; i < 14; ++i) cb[i] = nb[i];
    }
}

// ---------------------------------------------------------------------------
// Kernel 4 (merged u2 + layer2): one block per batch, 256 threads.
// Round-5 fixes:
//  * phase B buffers are FLOAT (28 VGPRs for cb+nb was the fp64 demand that
//    spilled to scratch at VGPR=52 -> 350 scratch round-trips = ~55us).
//  * lw2 row padded to 241 floats: the 10 m-lanes of one t read the same
//    column; m*240%32 in {0,16} was a 5-way conflict on EVERY bit-walk read
//    (351K conflict cycles). m*241%32 is all-distinct -> conflict-free.
//  * su2 row padded to 11 floats (coprime with 32) for phase C reads.
// ---------------------------------------------------------------------------
__global__ __launch_bounds__(256, 1) void u2l2(
        const unsigned long long* __restrict__ s1m,  // [NB][T][4]
        const float* __restrict__ w2,                // [N2][N1]
        float* __restrict__ out)                     // [NB][N2][T]
{
    __shared__ unsigned long long sm[T_BINS][4];   // 11.2 KB
    __shared__ float lw2[N2][N1 + 1];              // 9.6 KB (padded)
    __shared__ float su2[T_BINS][11];              // 15.4 KB (padded)

    const int tid = threadIdx.x;
    const int b   = blockIdx.x;

    for (int i = tid; i < N2 * N1; i += 256) lw2[i / N1][i % N1] = w2[i];
    {
        const unsigned long long* sp = s1m + (size_t)b * T_BINS * 4;
        unsigned long long* dp = &sm[0][0];
        for (int i = tid; i < T_BINS * 4; i += 256) dp[i] = sp[i];
    }
    __syncthreads();

    // ---- phase A: u2 = masks · w2 (kk asc / ffs asc -> bit-identical) ----
    for (int id = tid; id < T_BINS * N2; id += 256) {
        const int t = id / N2;
        const int m = id - t * N2;
        double acc = 0.0;
        #pragma unroll
        for (int kk = 0; kk < 4; ++kk) {
            unsigned long long msk = sm[t][kk];
            while (msk) {
                int j = __ffsll(msk) - 1;
                acc += (double)lw2[m][kk * 64 + j];
                msk &= msk - 1;
            }
        }
        su2[t][m] = (float)acc;
    }
    __syncthreads();

    // ---- phase B: layer-2 IIR on 10 lanes, float prefetch buffers ----
    if (tid < N2) {
        const int m = tid;
        DYN_CONSTS
        double p = 0.0, q = 0.0, P = 0.0, Q = 0.0;
        unsigned int hist = 0u;

        float cb[14], nb[14];
        #pragma unroll
        for (int i = 0; i < 14; ++i) cb[i] = su2[i][m];

        for (int t0 = 0; t0 < T_BINS; t0 += 14) {
            if (t0 + 14 < T_BINS) {
                #pragma unroll
                for (int i = 0; i < 14; ++i) nb[i] = su2[t0 + 14 + i][m];
            }
            #pragma unroll
            for (int i = 0; i < 14; ++i) {
                DYN_CORE((double)cb[i])
                su2[t0 + i][m] = (float)s;   // overwrite u2 with spike
            }
            #pragma unroll
            for (int i = 0; i < 14; ++i) cb[i] = nb[i];
        }
    }
    __syncthreads();

    // ---- phase C: coalesced store out[b][m][t] ----
    float* ob = out + (size_t)b * N2 * T_BINS;
    for (int id = tid; id < N2 * T_BINS; id += 256) {
        const int m = id / T_BINS;
        const int t = id - m * T_BINS;
        ob[id] = su2[t][m];
    }
}

// ---------------------------------------------------------------------------
extern "C" void kernel_launch(void* const* d_in, const int* in_sizes, int n_in,
                              void* d_out, int out_size, void* d_ws, size_t ws_size,
                              hipStream_t stream) {
    const int*   inp   = (const int*)d_in[0];    // [32,3,32,32]
    const int*   table = (const int*)d_in[1];    // [256]
    const float* w1    = (const float*)d_in[2];  // [240,3072]
    const float* w2    = (const float*)d_in[3];  // [10,240]
    float* out = (float*)d_out;                  // [32,10,350]

    char* ws = (char*)d_ws;
    size_t off = 0;
    float* W   = (float*)(ws + off);  off += (size_t)NB * WROWS * WROW * 4;  // 8.4 MB
    float* w1t = (float*)(ws + off);  off += (size_t)NPIX * N1 * 4;          // 2.9 MB
    unsigned long long* s1m = (unsigned long long*)(ws + off);
    off += (size_t)NB * T_BINS * 4 * 8;                                      // 358 KB
    int*   pix = (int*)(ws + off);    off += (size_t)NB * NPIX * 4;
    int*  offs = (int*)(ws + off);    off += (size_t)NB * NVAL * 4;
    int*  cnts = (int*)(ws + off);    off += (size_t)NB * NVAL * 4;
    int*   inv = (int*)(ws + off);    off += (size_t)T_BINS * 4;

    prep<<<NB + 192 + 1, 256, 0, stream>>>(inp, pix, offs, cnts, w1, w1t, table, inv);
    compute_w<<<dim3(NVAL / 4, NB), 256, 0, stream>>>(w1t, pix, offs, cnts, W);
    layer1_dyn<<<NB * 4, 64, 0, stream>>>(W, inv, s1m);
    u2l2<<<NB, 256, 0, stream>>>(s1m, w2, out);
}

// Round 7
// 142.888 us; speedup vs baseline: 1.6591x; 1.1868x over previous
//
#include <hip/hip_runtime.h>
#include <math.h>

#define T_BINS 350
#define REF_LEN 32
#define NB 32
#define NPIX 3072
#define N1 240
#define N2 10
#define NVAL 256
#define WROW 256                  // padded row width (floats) in W
#define WROWS (NVAL + 1)          // 256 value rows + 1 zero row
#define CH 14                     // chunk length (350 = 25*14)
#define NCHUNK 25

// ---------------------------------------------------------------------------
// Kernel 1 (fused): blocks 0..31 -> per-batch CSR build; blocks 32..223 ->
// 64x64 tiled transpose of w1; block 224 -> inverse bin map inv[t]=v or -1.
// (unchanged, proven)
// ---------------------------------------------------------------------------
__global__ void prep(const int* __restrict__ inp,
                     int* __restrict__ pix,    // [NB][NPIX]
                     int* __restrict__ offs,   // [NB][NVAL]
                     int* __restrict__ cnts,   // [NB][NVAL]
                     const float* __restrict__ w1,
                     float* __restrict__ w1t,
                     const int* __restrict__ table,
                     int* __restrict__ inv)    // [T_BINS]
{
    __shared__ int lc[NVAL];
    __shared__ int ls[NVAL];
    __shared__ int lslot[NVAL];
    __shared__ float tile[64][65];
    __shared__ int linv[T_BINS];

    const int tid = threadIdx.x;

    if (blockIdx.x < NB) {
        // ---- CSR build for batch b ----
        const int b = blockIdx.x;
        lc[tid] = 0;
        __syncthreads();

        int vals[12];
        #pragma unroll
        for (int i = 0; i < 12; ++i) {
            int v = inp[b * NPIX + i * 256 + tid];   // coalesced
            vals[i] = v;
            atomicAdd(&lc[v], 1);
        }
        __syncthreads();

        int x = lc[tid];
        ls[tid] = x;
        __syncthreads();
        for (int d = 1; d < 256; d <<= 1) {
            int y = (tid >= d) ? ls[tid - d] : 0;
            __syncthreads();
            ls[tid] += y;
            __syncthreads();
        }
        int excl = ls[tid] - x;
        offs[b * NVAL + tid] = excl;
        cnts[b * NVAL + tid] = x;
        lslot[tid] = excl;
        __syncthreads();

        #pragma unroll
        for (int i = 0; i < 12; ++i) {
            int slot = atomicAdd(&lslot[vals[i]], 1);
            pix[b * NPIX + slot] = i * 256 + tid;
        }
    } else if (blockIdx.x < NB + 192) {
        // ---- transpose tile ----
        const int tt = blockIdx.x - NB;       // 0..191
        const int p0 = (tt % 48) * 64;
        const int n0 = (tt / 48) * 64;
        const int c  = tid & 63;
        const int r0 = tid >> 6;              // 0..3

        #pragma unroll
        for (int i = 0; i < 16; ++i) {
            int n = n0 + r0 + i * 4;
            if (n < N1) tile[r0 + i * 4][c] = w1[n * NPIX + p0 + c];
        }
        __syncthreads();
        #pragma unroll
        for (int i = 0; i < 16; ++i) {
            int p = p0 + r0 + i * 4;
            int n = n0 + c;
            if (n < N1) w1t[p * N1 + n] = tile[c][r0 + i * 4];
        }
    } else {
        // ---- inverse bin map (table is injective value->bin) ----
        for (int i = tid; i < T_BINS; i += 256) linv[i] = -1;
        __syncthreads();
        if (tid < NVAL) linv[table[tid]] = tid;
        __syncthreads();
        for (int i = tid; i < T_BINS; i += 256) inv[i] = linv[i];
    }
}

// ---------------------------------------------------------------------------
// Kernel 2: W[b][v][n] = sum over pixels with value v of w1t[p, n].
// Padded layout [NB][257][256]: cols 240..255 = 0, row 256 = 0 -> the
// dynamics kernel loads UNCONDITIONALLY for every lane and every bin.
// Ascending-order fp64 accumulate, single fp32 rounding (verified).
// ---------------------------------------------------------------------------
__global__ void compute_w(const float* __restrict__ w1t,
                          const int* __restrict__ pix,
                          const int* __restrict__ offs,
                          const int* __restrict__ cnts,
                          float* __restrict__ W)     // [NB][WROWS][WROW]
{
    const int b   = blockIdx.y;
    const int tid = threadIdx.x;

    for (int vv = 0; vv < 4; ++vv) {
        const int v = blockIdx.x * 4 + vv;
        float outv = 0.0f;
        if (tid < N1) {
            const int cnt = cnts[b * NVAL + v];
            const int* pl = pix + b * NPIX + offs[b * NVAL + v];
            double acc = 0.0;
            int i = 0;
            for (; i + 4 <= cnt; i += 4) {
                int p0 = pl[i], p1 = pl[i + 1], p2 = pl[i + 2], p3 = pl[i + 3];
                double w0  = (double)w1t[p0 * N1 + tid];
                double w1v = (double)w1t[p1 * N1 + tid];
                double w2v = (double)w1t[p2 * N1 + tid];
                double w3  = (double)w1t[p3 * N1 + tid];
                acc += w0; acc += w1v; acc += w2v; acc += w3;   // ascending order
            }
            for (; i < cnt; ++i)
                acc += (double)w1t[pl[i] * N1 + tid];
            outv = (float)acc;
        }
        W[((size_t)b * WROWS + v) * WROW + tid] = outv;
    }
    // zero row (v = NVAL) for empty time bins
    if (blockIdx.x == 0)
        W[((size_t)b * WROWS + NVAL) * WROW + tid] = 0.0f;
}

// ---------------------------------------------------------------------------
// Dynamics math (identical constants/ops to all prior rounds).
// ---------------------------------------------------------------------------
#define DYN_CONSTS \
    const double A    = 0.9048374180359595;     \
    const double C    = 0.2718281828459045;     \
    const double Ar   = 0.36787944117144233;    \
    const double Cr   = -54.365636569180904;    \
    const double C31A = 1.0671679036256927e-12; \
    const double C31B = 3.4424771084699765e-14;

#define DYN_CORE(uin)                                         \
        q = A * (q + p);                                      \
        p = A * p + (uin);                                    \
        double vm = C * q + Cr * Q;                           \
        unsigned int sb = (vm >= 10.0) ? 1u : 0u;             \
        double s = (double)sb;                                \
        double sel31 = (hist & 0x80000000u) ? C31A : 0.0;     \
        double sel30 = (hist & 0x40000000u) ? C31B : 0.0;     \
        Q = Ar * (Q + P - sel31);                             \
        P = s + (Ar * P - sel30);                             \
        hist = (hist << 1) | sb;

// ---------------------------------------------------------------------------
// Kernel 3 (pipelined fusion): one block per batch, 512 threads = 8 waves.
// 3-stage software pipeline over 14-step chunks (the two 350-step serial
// IIR chains previously ran back-to-back in separate kernels; now they
// overlap on different SIMDs, lagged by 2 chunks):
//   waves 0-3 : layer-1 dynamics for chunk it   (round-6 verified shape:
//               float prefetch regs, unconditional padded-W loads, ballot)
//               -> masks to mbuf[it&1]
//   waves 4-6 : u2 bit-walk for chunk it-1 from mbuf[(it-1)&1] (verified
//               kk-asc/ffs-asc order, one (t,m) item per lane)
//               -> u2buf[(it-1)&1]
//   wave 7    : layer-2 IIR (10 lanes) for chunk it-2 from u2buf[it&1]
//               -> spikes into sout
// Single barrier per iteration; write slot c&1 vs read slot (c-1)&1 are
// disjoint every iteration, WAR hazards separated by the barrier.
// Eliminates the s1m and u2 global round-trips and one launch gap.
// ---------------------------------------------------------------------------
__global__ __launch_bounds__(512, 1) void fused_dyn(
        const float* __restrict__ W,     // [NB][WROWS][WROW]
        const int* __restrict__ inv,     // [T_BINS]
        const float* __restrict__ w2,    // [N2][N1]
        float* __restrict__ out)         // [NB][N2][T_BINS]
{
    __shared__ unsigned long long mbuf[2][CH][4];   // 896 B
    __shared__ float u2buf[2][CH][11];              // 1.2 KB (pad 11)
    __shared__ float sout[T_BINS][11];              // 15.4 KB (pad 11)
    __shared__ float lw2[N2][N1 + 1];               // 9.6 KB (pad 241)
    __shared__ int loff[T_BINS];                    // 1.4 KB

    const int tid  = threadIdx.x;
    const int b    = blockIdx.x;
    const int wid  = tid >> 6;
    const int lane = tid & 63;

    for (int i = tid; i < N2 * N1; i += 512) lw2[i / N1][i % N1] = w2[i];
    for (int i = tid; i < T_BINS; i += 512) {
        int v = inv[i];
        loff[i] = ((v >= 0) ? v : NVAL) * (WROW * 4);
    }
    __syncthreads();

    DYN_CONSTS
    double p = 0.0, q = 0.0, P = 0.0, Q = 0.0;   // IIR state: L1 (waves 0-3)
    unsigned int hist = 0u;                       // or L2 (wave 7, lane<10)

    float cb[14], nb[14];
    const char* wb = nullptr;
    if (wid < 4) {
        const int n = wid * 64 + lane;            // 0..255, legal (padded) col
        wb = (const char*)W + ((size_t)b * WROWS) * (WROW * 4) + (size_t)n * 4;
        #pragma unroll
        for (int j = 0; j < 14; ++j) cb[j] = *(const float*)(wb + loff[j]);
    }

    for (int it = 0; it < NCHUNK + 2; ++it) {
        if (wid < 4 && it < NCHUNK) {
            // ---- stage 1: layer-1 dynamics, chunk it ----
            if (it + 1 < NCHUNK) {
                const int base = (it + 1) * CH;
                int of[14];
                #pragma unroll
                for (int j = 0; j < 14; ++j) of[j] = loff[base + j];
                #pragma unroll
                for (int j = 0; j < 14; ++j) nb[j] = *(const float*)(wb + of[j]);
            }
            const int slot = it & 1;
            #pragma unroll
            for (int j = 0; j < 14; ++j) {
                DYN_CORE((double)cb[j])
                unsigned long long msk = __ballot(sb != 0u);
                if (lane == 0) mbuf[slot][j][wid] = msk;
            }
            #pragma unroll
            for (int j = 0; j < 14; ++j) cb[j] = nb[j];
        } else if (wid >= 4 && wid < 7 && it >= 1 && it <= NCHUNK) {
            // ---- stage 2: u2 for chunk it-1 (kk asc / ffs asc, verified) ----
            const int item = (wid - 4) * 64 + lane;   // 0..191, need 140
            if (item < CH * N2) {
                const int st = item / N2;
                const int m  = item - st * N2;
                const int slot = (it - 1) & 1;
                double acc = 0.0;
                #pragma unroll
                for (int kk = 0; kk < 4; ++kk) {
                    unsigned long long msk = mbuf[slot][st][kk];
                    while (msk) {
                        int j = __ffsll(msk) - 1;
                        acc += (double)lw2[m][kk * 64 + j];
                        msk &= msk - 1;
                    }
                }
                u2buf[slot][st][m] = (float)acc;
            }
        } else if (wid == 7 && lane < N2 && it >= 2) {
            // ---- stage 3: layer-2 IIR, chunk it-2 ----
            const int cl = it - 2;
            const int slot = cl & 1;
            const int m = lane;
            #pragma unroll
            for (int j = 0; j < 14; ++j) {
                DYN_CORE((double)u2buf[slot][j][m])
                sout[cl * CH + j][m] = (float)s;
            }
        }
        __syncthreads();
    }

    // ---- coalesced output out[b][m][t] ----
    float* ob = out + (size_t)b * N2 * T_BINS;
    for (int id = tid; id < N2 * T_BINS; id += 512) {
        const int m = id / T_BINS;
        const int t = id - m * T_BINS;
        ob[id] = sout[t][m];
    }
}

// ---------------------------------------------------------------------------
extern "C" void kernel_launch(void* const* d_in, const int* in_sizes, int n_in,
                              void* d_out, int out_size, void* d_ws, size_t ws_size,
                              hipStream_t stream) {
    const int*   inp   = (const int*)d_in[0];    // [32,3,32,32]
    const int*   table = (const int*)d_in[1];    // [256]
    const float* w1    = (const float*)d_in[2];  // [240,3072]
    const float* w2    = (const float*)d_in[3];  // [10,240]
    float* out = (float*)d_out;                  // [32,10,350]

    char* ws = (char*)d_ws;
    size_t off = 0;
    float* W   = (float*)(ws + off);  off += (size_t)NB * WROWS * WROW * 4;  // 8.4 MB
    float* w1t = (float*)(ws + off);  off += (size_t)NPIX * N1 * 4;          // 2.9 MB
    int*   pix = (int*)(ws + off);    off += (size_t)NB * NPIX * 4;
    int*  offs = (int*)(ws + off);    off += (size_t)NB * NVAL * 4;
    int*  cnts = (int*)(ws + off);    off += (size_t)NB * NVAL * 4;
    int*   inv = (int*)(ws + off);    off += (size_t)T_BINS * 4;

    prep<<<NB + 192 + 1, 256, 0, stream>>>(inp, pix, offs, cnts, w1, w1t, table, inv);
    compute_w<<<dim3(NVAL / 4, NB), 256, 0, stream>>>(w1t, pix, offs, cnts, W);
    fused_dyn<<<NB, 512, 0, stream>>>(W, inv, w2, out);
}

// Round 8
// 141.475 us; speedup vs baseline: 1.6756x; 1.0100x over previous
//
#include <hip/hip_runtime.h>
#include <math.h>

#define T_BINS 350
#define REF_LEN 32
#define NB 32
#define NPIX 3072
#define N1 240
#define N2 10
#define NVAL 256
#define WROW 256                  // padded row width (floats) in W
#define WROWS (NVAL + 1)          // 256 value rows + 1 zero row
#define CH 14                     // chunk length (350 = 25*14)
#define NCHUNK 25

// ---------------------------------------------------------------------------
// Kernel 1 (fused): blocks 0..31 -> per-batch CSR build; blocks 32..223 ->
// 64x64 tiled transpose of w1; block 224 -> inverse bin map inv[t]=v or -1.
// (unchanged, proven)
// ---------------------------------------------------------------------------
__global__ void prep(const int* __restrict__ inp,
                     int* __restrict__ pix,    // [NB][NPIX]
                     int* __restrict__ offs,   // [NB][NVAL]
                     int* __restrict__ cnts,   // [NB][NVAL]
                     const float* __restrict__ w1,
                     float* __restrict__ w1t,
                     const int* __restrict__ table,
                     int* __restrict__ inv)    // [T_BINS]
{
    __shared__ int lc[NVAL];
    __shared__ int ls[NVAL];
    __shared__ int lslot[NVAL];
    __shared__ float tile[64][65];
    __shared__ int linv[T_BINS];

    const int tid = threadIdx.x;

    if (blockIdx.x < NB) {
        // ---- CSR build for batch b ----
        const int b = blockIdx.x;
        lc[tid] = 0;
        __syncthreads();

        int vals[12];
        #pragma unroll
        for (int i = 0; i < 12; ++i) {
            int v = inp[b * NPIX + i * 256 + tid];   // coalesced
            vals[i] = v;
            atomicAdd(&lc[v], 1);
        }
        __syncthreads();

        int x = lc[tid];
        ls[tid] = x;
        __syncthreads();
        for (int d = 1; d < 256; d <<= 1) {
            int y = (tid >= d) ? ls[tid - d] : 0;
            __syncthreads();
            ls[tid] += y;
            __syncthreads();
        }
        int excl = ls[tid] - x;
        offs[b * NVAL + tid] = excl;
        cnts[b * NVAL + tid] = x;
        lslot[tid] = excl;
        __syncthreads();

        #pragma unroll
        for (int i = 0; i < 12; ++i) {
            int slot = atomicAdd(&lslot[vals[i]], 1);
            pix[b * NPIX + slot] = i * 256 + tid;
        }
    } else if (blockIdx.x < NB + 192) {
        // ---- transpose tile ----
        const int tt = blockIdx.x - NB;       // 0..191
        const int p0 = (tt % 48) * 64;
        const int n0 = (tt / 48) * 64;
        const int c  = tid & 63;
        const int r0 = tid >> 6;              // 0..3

        #pragma unroll
        for (int i = 0; i < 16; ++i) {
            int n = n0 + r0 + i * 4;
            if (n < N1) tile[r0 + i * 4][c] = w1[n * NPIX + p0 + c];
        }
        __syncthreads();
        #pragma unroll
        for (int i = 0; i < 16; ++i) {
            int p = p0 + r0 + i * 4;
            int n = n0 + c;
            if (n < N1) w1t[p * N1 + n] = tile[c][r0 + i * 4];
        }
    } else {
        // ---- inverse bin map (table is injective value->bin) ----
        for (int i = tid; i < T_BINS; i += 256) linv[i] = -1;
        __syncthreads();
        if (tid < NVAL) linv[table[tid]] = tid;
        __syncthreads();
        for (int i = tid; i < T_BINS; i += 256) inv[i] = linv[i];
    }
}

// ---------------------------------------------------------------------------
// Kernel 2: W[b][v][n] = sum over pixels with value v of w1t[p, n].
// Padded layout [NB][257][256]: cols 240..255 = 0, row 256 = 0 -> the
// dynamics kernel loads UNCONDITIONALLY for every lane and every bin.
// Ascending-order fp64 accumulate, single fp32 rounding (verified).
// ---------------------------------------------------------------------------
__global__ void compute_w(const float* __restrict__ w1t,
                          const int* __restrict__ pix,
                          const int* __restrict__ offs,
                          const int* __restrict__ cnts,
                          float* __restrict__ W)     // [NB][WROWS][WROW]
{
    const int b   = blockIdx.y;
    const int tid = threadIdx.x;

    for (int vv = 0; vv < 4; ++vv) {
        const int v = blockIdx.x * 4 + vv;
        float outv = 0.0f;
        if (tid < N1) {
            const int cnt = cnts[b * NVAL + v];
            const int* pl = pix + b * NPIX + offs[b * NVAL + v];
            double acc = 0.0;
            int i = 0;
            for (; i + 4 <= cnt; i += 4) {
                int p0 = pl[i], p1 = pl[i + 1], p2 = pl[i + 2], p3 = pl[i + 3];
                double w0  = (double)w1t[p0 * N1 + tid];
                double w1v = (double)w1t[p1 * N1 + tid];
                double w2v = (double)w1t[p2 * N1 + tid];
                double w3  = (double)w1t[p3 * N1 + tid];
                acc += w0; acc += w1v; acc += w2v; acc += w3;   // ascending order
            }
            for (; i < cnt; ++i)
                acc += (double)w1t[pl[i] * N1 + tid];
            outv = (float)acc;
        }
        W[((size_t)b * WROWS + v) * WROW + tid] = outv;
    }
    // zero row (v = NVAL) for empty time bins
    if (blockIdx.x == 0)
        W[((size_t)b * WROWS + NVAL) * WROW + tid] = 0.0f;
}

// ---------------------------------------------------------------------------
// Dynamics math (identical constants/ops to all prior rounds).
// ---------------------------------------------------------------------------
#define DYN_CONSTS \
    const double A    = 0.9048374180359595;     \
    const double C    = 0.2718281828459045;     \
    const double Ar   = 0.36787944117144233;    \
    const double Cr   = -54.365636569180904;    \
    const double C31A = 1.0671679036256927e-12; \
    const double C31B = 3.4424771084699765e-14;

#define DYN_CORE(uin)                                         \
        q = A * (q + p);                                      \
        p = A * p + (uin);                                    \
        double vm = C * q + Cr * Q;                           \
        unsigned int sb = (vm >= 10.0) ? 1u : 0u;             \
        double s = (double)sb;                                \
        double sel31 = (hist & 0x80000000u) ? C31A : 0.0;     \
        double sel30 = (hist & 0x40000000u) ? C31B : 0.0;     \
        Q = Ar * (Q + P - sel31);                             \
        P = s + (Ar * P - sel30);                             \
        hist = (hist << 1) | sb;

// expand M(i) for i = 0..13
#define F14(M) M(0) M(1) M(2) M(3) M(4) M(5) M(6) M(7) M(8) M(9) M(10) M(11) M(12) M(13)

// ---------------------------------------------------------------------------
// Kernel 3 (pipelined fusion): one block per batch, 512 threads = 8 waves.
// Same verified 3-stage / 2-slot pipeline as round 7. Round-8 change is
// PURELY codegen: the prefetch buffers are NAMED SCALARS (c0..c13/f0..f13,
// g0..g13), not arrays — round 7's VGPR_Count=36 proved the compiler
// demoted the arrays (or sank the loads to per-step use), costing ~400
// cycles of memory latency on every one of the 350 serial steps. An empty
// asm fence with "+v" constraints after each chain forces the 14 prefetched
// values to be register-resident, so the load latency is paid once per
// 14-step chunk and overlaps the fp64 IIR chain.
// ---------------------------------------------------------------------------
__global__ __launch_bounds__(512, 1) void fused_dyn(
        const float* __restrict__ W,     // [NB][WROWS][WROW]
        const int* __restrict__ inv,     // [T_BINS]
        const float* __restrict__ w2,    // [N2][N1]
        float* __restrict__ out)         // [NB][N2][T_BINS]
{
    __shared__ unsigned long long mbuf[2][CH][4];   // 896 B
    __shared__ float u2buf[2][CH][11];              // 1.2 KB (pad 11)
    __shared__ float sout[T_BINS][11];              // 15.4 KB (pad 11)
    __shared__ float lw2[N2][N1 + 1];               // 9.6 KB (pad 241)
    __shared__ int loff[T_BINS];                    // 1.4 KB

    const int tid  = threadIdx.x;
    const int b    = blockIdx.x;
    const int wid  = tid >> 6;
    const int lane = tid & 63;

    for (int i = tid; i < N2 * N1; i += 512) lw2[i / N1][i % N1] = w2[i];
    for (int i = tid; i < T_BINS; i += 512) {
        int v = inv[i];
        loff[i] = ((v >= 0) ? v : NVAL) * (WROW * 4);
    }
    __syncthreads();

    DYN_CONSTS
    double p = 0.0, q = 0.0, P = 0.0, Q = 0.0;   // IIR state: L1 (waves 0-3)
    unsigned int hist = 0u;                       // or L2 (wave 7, lane<10)

    // stage-1 prefetch state: named scalars, never an indexable object
#define DECL_CF(i) float c##i = 0.0f, f##i = 0.0f;
    F14(DECL_CF)

    const char* wb = nullptr;
    if (wid < 4) {
        const int n = wid * 64 + lane;            // 0..255, legal (padded) col
        wb = (const char*)W + ((size_t)b * WROWS) * (WROW * 4) + (size_t)n * 4;
#define LOADC(i) c##i = *(const float*)(wb + loff[i]);
        F14(LOADC)
    }

    for (int it = 0; it < NCHUNK + 2; ++it) {
        if (wid < 4 && it < NCHUNK) {
            // ---- stage 1: layer-1 dynamics, chunk it ----
            if (it + 1 < NCHUNK) {
                const int base = (it + 1) * CH;
#define LOADF(i) f##i = *(const float*)(wb + loff[base + i]);
                F14(LOADF)
            }
            const int slot = it & 1;
#define STEP1(i) { DYN_CORE((double)c##i)                                  \
                   unsigned long long msk = __ballot(sb != 0u);            \
                   if (lane == 0) mbuf[slot][i][wid] = msk; }
            F14(STEP1)
            // fence: force f0..f13 materialized in VGPRs here (loads may
            // not be sunk into next iteration's per-step uses)
            asm volatile("" : "+v"(f0), "+v"(f1), "+v"(f2), "+v"(f3),
                              "+v"(f4), "+v"(f5), "+v"(f6), "+v"(f7),
                              "+v"(f8), "+v"(f9), "+v"(f10), "+v"(f11),
                              "+v"(f12), "+v"(f13));
#define COPYC(i) c##i = f##i;
            F14(COPYC)
        } else if (wid >= 4 && wid < 7 && it >= 1 && it <= NCHUNK) {
            // ---- stage 2: u2 for chunk it-1 (kk asc / ffs asc, verified) ----
            const int item = (wid - 4) * 64 + lane;   // 0..191, need 140
            if (item < CH * N2) {
                const int st = item / N2;
                const int m  = item - st * N2;
                const int slot = (it - 1) & 1;
                double acc = 0.0;
                #pragma unroll
                for (int kk = 0; kk < 4; ++kk) {
                    unsigned long long msk = mbuf[slot][st][kk];
                    while (msk) {
                        int j = __ffsll(msk) - 1;
                        acc += (double)lw2[m][kk * 64 + j];
                        msk &= msk - 1;
                    }
                }
                u2buf[slot][st][m] = (float)acc;
            }
        } else if (wid == 7 && lane < N2 && it >= 2) {
            // ---- stage 3: layer-2 IIR, chunk it-2 ----
            const int cl = it - 2;
            const int slot = cl & 1;
            const int m = lane;
            const int tb = cl * CH;
#define DECL_G(i) float g##i = u2buf[slot][i][m];
            F14(DECL_G)
            asm volatile("" : "+v"(g0), "+v"(g1), "+v"(g2), "+v"(g3),
                              "+v"(g4), "+v"(g5), "+v"(g6), "+v"(g7),
                              "+v"(g8), "+v"(g9), "+v"(g10), "+v"(g11),
                              "+v"(g12), "+v"(g13));
#define STEP3(i) { DYN_CORE((double)g##i) sout[tb + i][m] = (float)s; }
            F14(STEP3)
        }
        __syncthreads();
    }

    // ---- coalesced output out[b][m][t] ----
    float* ob = out + (size_t)b * N2 * T_BINS;
    for (int id = tid; id < N2 * T_BINS; id += 512) {
        const int m = id / T_BINS;
        const int t = id - m * T_BINS;
        ob[id] = sout[t][m];
    }
}

// ---------------------------------------------------------------------------
extern "C" void kernel_launch(void* const* d_in, const int* in_sizes, int n_in,
                              void* d_out, int out_size, void* d_ws, size_t ws_size,
                              hipStream_t stream) {
    const int*   inp   = (const int*)d_in[0];    // [32,3,32,32]
    const int*   table = (const int*)d_in[1];    // [256]
    const float* w1    = (const float*)d_in[2];  // [240,3072]
    const float* w2    = (const float*)d_in[3];  // [10,240]
    float* out = (float*)d_out;                  // [32,10,350]

    char* ws = (char*)d_ws;
    size_t off = 0;
    float* W   = (float*)(ws + off);  off += (size_t)NB * WROWS * WROW * 4;  // 8.4 MB
    float* w1t = (float*)(ws + off);  off += (size_t)NPIX * N1 * 4;          // 2.9 MB
    int*   pix = (int*)(ws + off);    off += (size_t)NB * NPIX * 4;
    int*  offs = (int*)(ws + off);    off += (size_t)NB * NVAL * 4;
    int*  cnts = (int*)(ws + off);    off += (size_t)NB * NVAL * 4;
    int*   inv = (int*)(ws + off);    off += (size_t)T_BINS * 4;

    prep<<<NB + 192 + 1, 256, 0, stream>>>(inp, pix, offs, cnts, w1, w1t, table, inv);
    compute_w<<<dim3(NVAL / 4, NB), 256, 0, stream>>>(w1t, pix, offs, cnts, W);
    fused_dyn<<<NB, 512, 0, stream>>>(W, inv, w2, out);
}